// Round 4
// baseline (399.521 us; speedup 1.0000x reference)
//
#include <hip/hip_runtime.h>

// RecursiveNN — MFMA f16, LDS-staged 2D-tile A-build.
// 16x8 pixel tiles, 128 px/block, 256 threads.
// z1/z2 stored f16 in ws. W1/W2 B-fragments in registers (L2-resident loads).
// One barrier per block (post-staging); all A-build writes are own-wave-slice.

namespace {
constexpr int NB = 16;
constexpr int ND = 12;
}

typedef __attribute__((ext_vector_type(8))) _Float16 f16x8;
typedef __attribute__((ext_vector_type(8))) short   s16x8;
typedef __attribute__((ext_vector_type(4))) float   f32x4;

__device__ __forceinline__ unsigned short f2h(float f) {
    return __builtin_bit_cast(unsigned short, (_Float16)f);   // RNE
}
__device__ __forceinline__ float h2f(unsigned short h) {
    return (float)__builtin_bit_cast(_Float16, h);
}

// ---------------- perceive: x [NB,ND,H,W] f32 -> z [NB,4*ND,H,W] f16 --------
template<int H, int W, int LH, int LW>
__global__ __launch_bounds__(256)
void perceive_kernel(const float* __restrict__ x, unsigned short* __restrict__ z) {
    int idx = blockIdx.x * 256 + threadIdx.x;
    int xx = idx & (W - 1);
    int yy = (idx >> LW) & (H - 1);
    int bc = idx >> (LW + LH);            // b*ND + c
    const float* p = x + bc * H * W;
    int ym = (yy - 1) & (H - 1), yp = (yy + 1) & (H - 1);
    int xm = (xx - 1) & (W - 1), xq = (xx + 1) & (W - 1);
    float n00 = p[ym*W+xm], n01 = p[ym*W+xx], n02 = p[ym*W+xq];
    float n10 = p[yy*W+xm], n11 = p[yy*W+xx], n12 = p[yy*W+xq];
    float n20 = p[yp*W+xm], n21 = p[yp*W+xx], n22 = p[yp*W+xq];
    float sx  = (n02 - n00) + 2.f*(n12 - n10) + (n22 - n20);
    float sy  = (n20 - n00) + 2.f*(n21 - n01) + (n22 - n02);
    float lap = n00 + 2.f*n01 + n02 + 2.f*n10 - 12.f*n11 + 2.f*n12
              + n20 + 2.f*n21 + n22;
    unsigned short* zp = z + (bc * 4) * (H * W) + yy * W + xx;
    zp[0]       = f2h(n11);
    zp[H*W]     = f2h(sx);
    zp[2*H*W]   = f2h(sy);
    zp[3*H*W]   = f2h(lap);
}

// ---------------- fused per-resolution MFMA kernel --------------------------
// RES0: x0f (perceive fused via LDS-staged tile), zc=z1 f16 (upsample)
// RES1: zin=z1 f16 (direct),                      zc=z2 f16 (upsample)
// RES2: zin=z2 f16 (direct, K padded to 64),      xres=x2 f32 (residual)
template<int RES>
__global__ __launch_bounds__(256, 3)
void res_mfma(const float* __restrict__ x0f,
              const unsigned short* __restrict__ zin,
              const unsigned short* __restrict__ zc,
              const float* __restrict__ xres,
              const float* __restrict__ w1,
              const float* __restrict__ b1,
              const float* __restrict__ w2,
              float* __restrict__ out)
{
    constexpr int H  = (RES==0)?256:(RES==1)?128:64;
    constexpr int W  = H;
    constexpr int Hc = H/2, Wc = W/2;
    constexpr int HW = H*W, HcWc = Hc*Wc;
    constexpr int LBPX = (RES==0)?4:(RES==1)?3:2;   // log2(W/16)
    constexpr int BPI  = (H/8) * (W/16);
    constexpr int K1   = (RES==2)?48:96;            // real inner dim of w1
    constexpr int KPAD = (RES==2)?64:96;
    constexpr int NK   = KPAD/32;
    constexpr int KP   = 104;                       // Alds row stride (f16)

    __shared__ unsigned short Alds[128*KP];         // A, then reused for H
    __shared__ float          SxF[(RES==0)?2160:1]; // x0 tile [12][10][18]
    __shared__ unsigned short SzH[(RES!=2)?2880:1]; // coarse z tile [48][6][10]

    const int tid = threadIdx.x;
    const int gid = blockIdx.x;
    const int b   = gid / BPI;
    const int rem = gid - b*BPI;
    const int txi = rem & ((1<<LBPX)-1);
    const int tyi = rem >> LBPX;
    const int tx  = txi*16, ty = tyi*8;

    const int wid = tid >> 6, lane = tid & 63;
    const int fr  = lane & 15, g = lane >> 4;

    // ================= staging (coalesced global -> LDS) =================
    if (RES == 0) {
        const float* bp = x0f + b*ND*HW;
#pragma unroll
        for (int i = 0; i < 9; ++i) {
            int e = i*256 + tid;
            if (e < 2160) {
                int ci = e % 18; int t = e / 18;
                int ri = t % 10; int c = t / 10;
                int gy = (ty - 1 + ri) & (H-1);
                int gx = (tx - 1 + ci) & (W-1);
                SxF[e] = bp[c*HW + gy*W + gx];
            }
        }
    }
    if (RES != 2) {
        const unsigned short* zb = zc + b*48*HcWc;
        int r0 = (ty>>1) - 1, c0 = (tx>>1) - 1;
#pragma unroll
        for (int i = 0; i < 12; ++i) {
            int e = i*256 + tid;
            if (e < 2880) {
                int ci = e % 10; int t = e / 10;
                int ri = t % 6;  int k = t / 6;
                int gy = min(max(r0+ri, 0), Hc-1);
                int gx = min(max(c0+ci, 0), Wc-1);
                SzH[e] = zb[k*HcWc + gy*Wc + gx];
            }
        }
        __syncthreads();
    }

    // ================= build A rows [wid*32, wid*32+32) =================
    if (RES == 0) {
        // stencil features 0..47 from staged x0 tile
#pragma unroll
        for (int i = 0; i < 6; ++i) {
            int t  = i*64 + lane;          // 384 tasks/wave: 32 rows x 12 ch
            int c  = t >> 5;
            int pr = t & 31;
            int p  = wid*32 + pr;
            int py = p >> 4, px = p & 15;
            const float* S = &SxF[c*180 + py*18 + px];
            float n00=S[0],  n01=S[1],  n02=S[2];
            float n10=S[18], n11=S[19], n12=S[20];
            float n20=S[36], n21=S[37], n22=S[38];
            float sx  = (n02-n00) + 2.f*(n12-n10) + (n22-n20);
            float sy  = (n20-n00) + 2.f*(n21-n01) + (n22-n02);
            float lap = n00+2.f*n01+n02+2.f*n10-12.f*n11+2.f*n12+n20+2.f*n21+n22;
            uint2 pk;
            pk.x = (unsigned)f2h(n11) | ((unsigned)f2h(sx)  << 16);
            pk.y = (unsigned)f2h(sy)  | ((unsigned)f2h(lap) << 16);
            *(uint2*)&Alds[p*KP + 4*c] = pk;
        }
    } else {
        // direct f16 copy of own-level z (features 0..47)
        int pr = lane >> 1, half = lane & 1;
        int p  = wid*32 + pr;
        const unsigned short* q0 = zin + b*48*HW + (ty + (p>>4))*W + tx + (p&15);
#pragma unroll
        for (int i = 0; i < 24; ++i) {
            int k = half*24 + i;
            Alds[p*KP + k] = q0[k*HW];
        }
        if (RES == 2) {
#pragma unroll
            for (int j = 0; j < 8; ++j)
                Alds[p*KP + 48 + half*8 + j] = 0;
        }
    }
    if (RES != 2) {
        // bilinear upsample features 48..95 from staged coarse tile
        int pr = lane >> 1, half = lane & 1;
        int p  = wid*32 + pr;
        int py = p >> 4, px = p & 15;
        int sy0 = (py>>1) + (py&1);
        int sx0 = (px>>1) + (px&1);
        float wy1 = (py&1) ? 0.25f : 0.75f, wy0 = 1.f - wy1;
        float wx1 = (px&1) ? 0.25f : 0.75f, wx0 = 1.f - wx1;
        float w00 = wy0*wx0, w01 = wy0*wx1, w10 = wy1*wx0, w11 = wy1*wx1;
#pragma unroll
        for (int i = 0; i < 24; ++i) {
            int k = half*24 + i;
            const unsigned short* Sz = &SzH[k*60 + sy0*10 + sx0];
            float v = w00*h2f(Sz[0])  + w01*h2f(Sz[1])
                    + w10*h2f(Sz[10]) + w11*h2f(Sz[11]);
            Alds[p*KP + 48 + k] = f2h(v);
        }
    }

    // ================= weight fragments in registers =================
    f16x8 bfrag[6][NK];
#pragma unroll
    for (int nt = 0; nt < 6; ++nt)
#pragma unroll
        for (int ks = 0; ks < NK; ++ks) {
            int row = nt*16 + fr, col = ks*32 + g*8;
            f16x8 f;
            if (RES == 2 && col >= 48) {
#pragma unroll
                for (int j = 0; j < 8; ++j) f[j] = (_Float16)0.f;
            } else {
                const float* s = w1 + row*K1 + col;
                float4 lo = *(const float4*)s;
                float4 hi = *(const float4*)(s+4);
                f[0]=(_Float16)lo.x; f[1]=(_Float16)lo.y;
                f[2]=(_Float16)lo.z; f[3]=(_Float16)lo.w;
                f[4]=(_Float16)hi.x; f[5]=(_Float16)hi.y;
                f[6]=(_Float16)hi.z; f[7]=(_Float16)hi.w;
            }
            bfrag[nt][ks] = f;
        }

    f16x8 b2frag[3];
#pragma unroll
    for (int ks = 0; ks < 3; ++ks) {
        f16x8 f;
        if (fr < 12) {
            const float* s = w2 + fr*96 + ks*32 + g*8;
            float4 lo = *(const float4*)s;
            float4 hi = *(const float4*)(s+4);
            f[0]=(_Float16)lo.x; f[1]=(_Float16)lo.y;
            f[2]=(_Float16)lo.z; f[3]=(_Float16)lo.w;
            f[4]=(_Float16)hi.x; f[5]=(_Float16)hi.y;
            f[6]=(_Float16)hi.z; f[7]=(_Float16)hi.w;
        } else {
#pragma unroll
            for (int j = 0; j < 8; ++j) f[j] = (_Float16)0.f;
        }
        b2frag[ks] = f;
    }

    float bv[6];
#pragma unroll
    for (int nt = 0; nt < 6; ++nt) bv[nt] = b1[nt*16 + fr];

    // ================= layer 1 MFMA =================
    f32x4 acc[2][6] = {};
#pragma unroll
    for (int ks = 0; ks < NK; ++ks) {
        f16x8 a0 = __builtin_bit_cast(f16x8, *(const s16x8*)&Alds[(wid*32 +      fr)*KP + ks*32 + g*8]);
        f16x8 a1 = __builtin_bit_cast(f16x8, *(const s16x8*)&Alds[(wid*32 + 16 + fr)*KP + ks*32 + g*8]);
#pragma unroll
        for (int nt = 0; nt < 6; ++nt) {
            acc[0][nt] = __builtin_amdgcn_mfma_f32_16x16x32_f16(a0, bfrag[nt][ks], acc[0][nt], 0, 0, 0);
            acc[1][nt] = __builtin_amdgcn_mfma_f32_16x16x32_f16(a1, bfrag[nt][ks], acc[1][nt], 0, 0, 0);
        }
    }

    // bias + relu -> H (f16) back into own Alds slice (in-wave ordering)
#pragma unroll
    for (int nt = 0; nt < 6; ++nt)
#pragma unroll
        for (int m = 0; m < 2; ++m)
#pragma unroll
            for (int rg = 0; rg < 4; ++rg) {
                float h = fmaxf(acc[m][nt][rg] + bv[nt], 0.f);
                Alds[(wid*32 + m*16 + g*4 + rg)*KP + nt*16 + fr] = f2h(h);
            }

    // ================= layer 2 MFMA (K=96, N=16 padded) =================
    f32x4 acc2[2] = {};
#pragma unroll
    for (int ks = 0; ks < 3; ++ks)
#pragma unroll
        for (int m = 0; m < 2; ++m) {
            f16x8 ah = __builtin_bit_cast(f16x8, *(const s16x8*)&Alds[(wid*32 + m*16 + fr)*KP + ks*32 + g*8]);
            acc2[m] = __builtin_amdgcn_mfma_f32_16x16x32_f16(ah, b2frag[ks], acc2[m], 0, 0, 0);
        }

    // ================= store =================
    if (fr < 12) {
        const int chbase = (b*ND + fr)*HW;
#pragma unroll
        for (int m = 0; m < 2; ++m) {
            int gy = ty + wid*2 + m;
            int gx = tx + g*4;
            float4 vv;
            vv.x = acc2[m][0]; vv.y = acc2[m][1];
            vv.z = acc2[m][2]; vv.w = acc2[m][3];
            if (RES == 2) {
                const float4 rr = *(const float4*)&xres[chbase + gy*W + gx];
                vv.x += rr.x; vv.y += rr.y; vv.z += rr.z; vv.w += rr.w;
            }
            *(float4*)&out[chbase + gy*W + gx] = vv;
        }
    }
}

extern "C" void kernel_launch(void* const* d_in, const int* in_sizes, int n_in,
                              void* d_out, int out_size, void* d_ws, size_t ws_size,
                              hipStream_t stream) {
    const float* x0   = (const float*)d_in[0];
    const float* x1   = (const float*)d_in[1];
    const float* x2   = (const float*)d_in[2];
    const float* w0_1 = (const float*)d_in[3];
    const float* b0_1 = (const float*)d_in[4];
    const float* w0_2 = (const float*)d_in[5];
    const float* w1_1 = (const float*)d_in[6];
    const float* b1_1 = (const float*)d_in[7];
    const float* w1_2 = (const float*)d_in[8];
    const float* w2_1 = (const float*)d_in[9];
    const float* b2_1 = (const float*)d_in[10];
    const float* w2_2 = (const float*)d_in[11];
    float* out = (float*)d_out;

    unsigned short* z1h = (unsigned short*)d_ws;        // [16,48,128,128] f16
    unsigned short* z2h = z1h + NB * 48 * 128 * 128;    // [16,48,64,64]  f16

    perceive_kernel<128,128,7,7><<<NB*ND*128*128/256, 256, 0, stream>>>(x1, z1h);
    perceive_kernel< 64, 64,6,6><<<NB*ND*64*64/256,   256, 0, stream>>>(x2, z2h);

    res_mfma<0><<<NB*512, 256, 0, stream>>>(x0, nullptr, z1h, nullptr,
                                            w0_1, b0_1, w0_2, out);
    res_mfma<1><<<NB*128, 256, 0, stream>>>(nullptr, z1h, z2h, nullptr,
                                            w1_1, b1_1, w1_2,
                                            out + NB*ND*256*256);
    res_mfma<2><<<NB*32,  256, 0, stream>>>(nullptr, z2h, nullptr, x2,
                                            w2_1, b2_1, w2_2,
                                            out + NB*ND*256*256 + NB*ND*128*128);
}

// Round 5
// 310.996 us; speedup vs baseline: 1.2847x; 1.2847x over previous
//
#include <hip/hip_runtime.h>

// RecursiveNN — MFMA f16, staged 2D-tile A-build, fragment-native LDS layouts.
// A/H in LDS as [kgroup][row][8] (16B-sequential MFMA reads, conflict-free).
// W1 in LDS as [kgroup][n][8]; W2 fragments in regs (12 VGPR); weights
// pre-converted to f16 in ws by cvtw kernel. One barrier per block.

namespace {
constexpr int NB = 16;
constexpr int ND = 12;
}

typedef __attribute__((ext_vector_type(8))) _Float16 f16x8;
typedef __attribute__((ext_vector_type(8))) short   s16x8;
typedef __attribute__((ext_vector_type(4))) float   f32x4;

__device__ __forceinline__ unsigned short f2h(float f) {
    return __builtin_bit_cast(unsigned short, (_Float16)f);   // RNE
}
__device__ __forceinline__ float h2f(unsigned short h) {
    return (float)__builtin_bit_cast(_Float16, h);
}

// ---------------- perceive: x [NB,ND,H,W] f32 -> z [NB,4*ND,H,W] f16 --------
template<int H, int W, int LH, int LW>
__global__ __launch_bounds__(256)
void perceive_kernel(const float* __restrict__ x, unsigned short* __restrict__ z) {
    int idx = blockIdx.x * 256 + threadIdx.x;
    int xx = idx & (W - 1);
    int yy = (idx >> LW) & (H - 1);
    int bc = idx >> (LW + LH);            // b*ND + c
    const float* p = x + bc * H * W;
    int ym = (yy - 1) & (H - 1), yp = (yy + 1) & (H - 1);
    int xm = (xx - 1) & (W - 1), xq = (xx + 1) & (W - 1);
    float n00 = p[ym*W+xm], n01 = p[ym*W+xx], n02 = p[ym*W+xq];
    float n10 = p[yy*W+xm], n11 = p[yy*W+xx], n12 = p[yy*W+xq];
    float n20 = p[yp*W+xm], n21 = p[yp*W+xx], n22 = p[yp*W+xq];
    float sx  = (n02 - n00) + 2.f*(n12 - n10) + (n22 - n20);
    float sy  = (n20 - n00) + 2.f*(n21 - n01) + (n22 - n02);
    float lap = n00 + 2.f*n01 + n02 + 2.f*n10 - 12.f*n11 + 2.f*n12
              + n20 + 2.f*n21 + n22;
    unsigned short* zp = z + (bc * 4) * (H * W) + yy * W + xx;
    zp[0]       = f2h(n11);
    zp[H*W]     = f2h(sx);
    zp[2*H*W]   = f2h(sy);
    zp[3*H*W]   = f2h(lap);
}

// ---------------- weight conversion f32 -> f16 (once) -----------------------
__global__ __launch_bounds__(256)
void cvtw_kernel(const float* __restrict__ s0, const float* __restrict__ s1,
                 const float* __restrict__ s2, const float* __restrict__ s3,
                 const float* __restrict__ s4, const float* __restrict__ s5,
                 unsigned short* __restrict__ d) {
    int i = blockIdx.x * 256 + threadIdx.x;
    if (i >= 26496) return;
    const float* s; int off;
    if      (i <  9216) { s = s0; off = 0;     }
    else if (i < 10368) { s = s1; off = 9216;  }
    else if (i < 19584) { s = s2; off = 10368; }
    else if (i < 20736) { s = s3; off = 19584; }
    else if (i < 25344) { s = s4; off = 20736; }
    else                { s = s5; off = 25344; }
    d[i] = f2h(s[i - off]);
}

// ---------------- fused per-resolution MFMA kernel --------------------------
template<int RES>
__global__ __launch_bounds__(256, 3)
void res_mfma(const float* __restrict__ x0f,
              const unsigned short* __restrict__ zin,
              const unsigned short* __restrict__ zc,
              const float* __restrict__ xres,
              const unsigned short* __restrict__ w1h,   // f16 [96][K1]
              const float* __restrict__ b1,
              const unsigned short* __restrict__ w2h,   // f16 [12][96]
              float* __restrict__ out)
{
    constexpr int H   = (RES==0)?256:(RES==1)?128:64;
    constexpr int W   = H;
    constexpr int Hc  = H/2, Wc = W/2;
    constexpr int HW  = H*W, HcWc = Hc*Wc;
    constexpr int LBPX= (RES==0)?4:(RES==1)?3:2;    // log2(W/16)
    constexpr int BPI = (H/8)*(W/16);
    constexpr int K1  = (RES==2)?48:96;             // real inner dim of w1
    constexpr int NKG = (RES==2)?8:12;              // layer-1 A/W kgroups
    constexpr int NK  = (RES==2)?2:3;               // layer-1 k-steps

    __shared__ unsigned short Alds[12*128*8];       // [kg][row][8]; A then H
    __shared__ unsigned short Wf[NKG*96*8];         // [kg][n][8]
    __shared__ unsigned short SxF[(RES==0)?2160:8]; // x0 tile f16 [12][10][18]
    __shared__ unsigned short SzH[(RES!=2)?2880:8]; // coarse z tile [48][6][10]

    const int tid = threadIdx.x;
    // XCD-bijective swizzle (grid % 8 == 0 for all RES)
    const int nwg = gridDim.x;
    const int cpx = nwg >> 3;
    const int bid = blockIdx.x;
    const int gid = (bid & 7) * cpx + (bid >> 3);

    const int b   = gid / BPI;
    const int rem = gid - b*BPI;
    const int txi = rem & ((1<<LBPX)-1);
    const int tyi = rem >> LBPX;
    const int tx  = txi*16, ty = tyi*8;

    const int wid = tid >> 6, lane = tid & 63;
    const int fr  = lane & 15, g = lane >> 4;

    // ================= staging (pre-barrier) =================
    if (RES == 0) {
        const float* bp = x0f + b*ND*HW;
#pragma unroll
        for (int i = 0; i < 9; ++i) {
            int e = i*256 + tid;
            if (e < 2160) {
                int ci = e % 18; int t = e / 18;
                int ri = t % 10; int c = t / 10;
                int gy = (ty - 1 + ri) & (H-1);
                int gx = (tx - 1 + ci) & (W-1);
                SxF[e] = f2h(bp[c*HW + gy*W + gx]);
            }
        }
    }
    if (RES != 2) {
        const unsigned short* zb = zc + b*48*HcWc;
        int r0 = (ty>>1) - 1, c0 = (tx>>1) - 1;
#pragma unroll
        for (int i = 0; i < 12; ++i) {
            int e = i*256 + tid;
            if (e < 2880) {
                int ci = e % 10; int t = e / 10;
                int ri = t % 6;  int k = t / 6;
                int gy = min(max(r0+ri, 0), Hc-1);
                int gx = min(max(c0+ci, 0), Wc-1);
                SzH[e] = zb[k*HcWc + gy*Wc + gx];
            }
        }
    }
    // W1 -> LDS fragment layout [kg][n][8]
    {
        constexpr int NCH = NKG*96;
#pragma unroll
        for (int i = 0; i < (NCH+255)/256; ++i) {
            int q = i*256 + tid;
            if (q < NCH) {
                int kg = q / 96, n = q - kg*96;
                s16x8 v = {0,0,0,0,0,0,0,0};
                if (!(RES==2 && kg >= 6))
                    v = *(const s16x8*)&w1h[n*K1 + kg*8];
                *(s16x8*)&Wf[(kg*96 + n)*8] = v;
            }
        }
    }
    __syncthreads();

    // ================= build A rows [wid*32, wid*32+32) =================
    if (RES == 0) {
        // stencil features 0..47 (kg 0..5) from staged x0 tile
#pragma unroll
        for (int i = 0; i < 6; ++i) {
            int t  = i*64 + lane;          // 12 ch x 32 rows per wave
            int c  = t >> 5;
            int p  = wid*32 + (t & 31);
            int py = p >> 4, px = p & 15;
            const unsigned short* S = &SxF[c*180 + py*18 + px];
            float n00=h2f(S[0]),  n01=h2f(S[1]),  n02=h2f(S[2]);
            float n10=h2f(S[18]), n11=h2f(S[19]), n12=h2f(S[20]);
            float n20=h2f(S[36]), n21=h2f(S[37]), n22=h2f(S[38]);
            float sx  = (n02-n00) + 2.f*(n12-n10) + (n22-n20);
            float sy  = (n20-n00) + 2.f*(n21-n01) + (n22-n02);
            float lap = n00+2.f*n01+n02+2.f*n10-12.f*n11+2.f*n12+n20+2.f*n21+n22;
            uint2 pk;
            pk.x = (unsigned)f2h(n11) | ((unsigned)f2h(sx)  << 16);
            pk.y = (unsigned)f2h(sy)  | ((unsigned)f2h(lap) << 16);
            // k = 4c -> kg = c>>1, off = 4*(c&1)
            *(uint2*)&Alds[(c>>1)*1024 + p*8 + 4*(c&1)] = pk;
        }
    } else {
        // direct f16 copy of own-level z: kg 0..5, 8-ch chunks
#pragma unroll
        for (int j = 0; j < 3; ++j) {
            int cc = j*64 + lane;
            int kg = cc >> 5, p = wid*32 + (cc & 31);
            int gy = ty + (p>>4), gx = tx + (p&15);
            const unsigned short* q0 = zin + (b*48 + kg*8)*HW + gy*W + gx;
            s16x8 v;
#pragma unroll
            for (int jj = 0; jj < 8; ++jj) v[jj] = (short)q0[jj*HW];
            *(s16x8*)&Alds[kg*1024 + p*8] = v;
        }
        if (RES == 2) {   // zero-pad kg 6,7
            int kg = 6 + (lane & 1), p = wid*32 + (lane >> 1);
            s16x8 z = {0,0,0,0,0,0,0,0};
            *(s16x8*)&Alds[kg*1024 + p*8] = z;
        }
    }
    if (RES != 2) {
        // bilinear upsample features 48..95 (kg 6..11), 8-ch chunks
#pragma unroll
        for (int j = 0; j < 3; ++j) {
            int cc  = j*64 + lane;
            int kgl = cc >> 5, p = wid*32 + (cc & 31);
            int py = p >> 4, px = p & 15;
            int sy0 = (py>>1) + (py&1);
            int sx0 = (px>>1) + (px&1);
            float wy1 = (py&1) ? 0.25f : 0.75f, wy0 = 1.f - wy1;
            float wx1 = (px&1) ? 0.25f : 0.75f, wx0 = 1.f - wx1;
            float w00 = wy0*wx0, w01 = wy0*wx1, w10 = wy1*wx0, w11 = wy1*wx1;
            s16x8 v;
#pragma unroll
            for (int jj = 0; jj < 8; ++jj) {
                const unsigned short* Sz = &SzH[(kgl*8 + jj)*60 + sy0*10 + sx0];
                float val = w00*h2f(Sz[0])  + w01*h2f(Sz[1])
                          + w10*h2f(Sz[10]) + w11*h2f(Sz[11]);
                v[jj] = (short)f2h(val);
            }
            *(s16x8*)&Alds[(6+kgl)*1024 + p*8] = v;
        }
    }

    // ================= W2 fragments (12 VGPR) + biases =================
    f16x8 b2f[3];
#pragma unroll
    for (int ks = 0; ks < 3; ++ks) {
        s16x8 v = {0,0,0,0,0,0,0,0};
        if (fr < 12) v = *(const s16x8*)&w2h[fr*96 + ks*32 + g*8];
        b2f[ks] = __builtin_bit_cast(f16x8, v);
    }
    float bv[6];
#pragma unroll
    for (int nt = 0; nt < 6; ++nt) bv[nt] = b1[nt*16 + fr];

    // ================= layer 1 MFMA =================
    f32x4 acc[2][6] = {};
#pragma unroll
    for (int ks = 0; ks < NK; ++ks) {
        const int kga = ks*4 + g;
        f16x8 a0 = __builtin_bit_cast(f16x8, *(const s16x8*)&Alds[kga*1024 + (wid*32      + fr)*8]);
        f16x8 a1 = __builtin_bit_cast(f16x8, *(const s16x8*)&Alds[kga*1024 + (wid*32 + 16 + fr)*8]);
#pragma unroll
        for (int nt = 0; nt < 6; ++nt) {
            f16x8 bb = __builtin_bit_cast(f16x8, *(const s16x8*)&Wf[kga*768 + (nt*16 + fr)*8]);
            acc[0][nt] = __builtin_amdgcn_mfma_f32_16x16x32_f16(a0, bb, acc[0][nt], 0, 0, 0);
            acc[1][nt] = __builtin_amdgcn_mfma_f32_16x16x32_f16(a1, bb, acc[1][nt], 0, 0, 0);
        }
    }

    // bias + relu -> H (f16) into own Alds slice (in-wave ordering)
#pragma unroll
    for (int nt = 0; nt < 6; ++nt)
#pragma unroll
        for (int m = 0; m < 2; ++m)
#pragma unroll
            for (int rg = 0; rg < 4; ++rg) {
                float h = fmaxf(acc[m][nt][rg] + bv[nt], 0.f);
                int k = nt*16 + fr;
                int row = wid*32 + m*16 + g*4 + rg;
                Alds[(k>>3)*1024 + row*8 + (k&7)] = f2h(h);
            }

    // ================= layer 2 MFMA (K=96, N=16 padded) =================
    f32x4 acc2[2] = {};
#pragma unroll
    for (int ks = 0; ks < 3; ++ks) {
        const int kga = ks*4 + g;
#pragma unroll
        for (int m = 0; m < 2; ++m) {
            f16x8 ah = __builtin_bit_cast(f16x8, *(const s16x8*)&Alds[kga*1024 + (wid*32 + m*16 + fr)*8]);
            acc2[m] = __builtin_amdgcn_mfma_f32_16x16x32_f16(ah, b2f[ks], acc2[m], 0, 0, 0);
        }
    }

    // ================= store =================
    if (fr < 12) {
        const int chbase = (b*ND + fr)*HW;
#pragma unroll
        for (int m = 0; m < 2; ++m) {
            int gy = ty + wid*2 + m;
            int gx = tx + g*4;
            float4 vv;
            vv.x = acc2[m][0]; vv.y = acc2[m][1];
            vv.z = acc2[m][2]; vv.w = acc2[m][3];
            if (RES == 2) {
                const float4 rr = *(const float4*)&xres[chbase + gy*W + gx];
                vv.x += rr.x; vv.y += rr.y; vv.z += rr.z; vv.w += rr.w;
            }
            *(float4*)&out[chbase + gy*W + gx] = vv;
        }
    }
}

extern "C" void kernel_launch(void* const* d_in, const int* in_sizes, int n_in,
                              void* d_out, int out_size, void* d_ws, size_t ws_size,
                              hipStream_t stream) {
    const float* x0   = (const float*)d_in[0];
    const float* x1   = (const float*)d_in[1];
    const float* x2   = (const float*)d_in[2];
    const float* w0_1 = (const float*)d_in[3];
    const float* b0_1 = (const float*)d_in[4];
    const float* w0_2 = (const float*)d_in[5];
    const float* w1_1 = (const float*)d_in[6];
    const float* b1_1 = (const float*)d_in[7];
    const float* w1_2 = (const float*)d_in[8];
    const float* w2_1 = (const float*)d_in[9];
    const float* b2_1 = (const float*)d_in[10];
    const float* w2_2 = (const float*)d_in[11];
    float* out = (float*)d_out;

    unsigned short* z1h = (unsigned short*)d_ws;        // [16,48,128,128] f16
    unsigned short* z2h = z1h + NB*48*128*128;          // [16,48,64,64]  f16
    unsigned short* wh  = z2h + NB*48*64*64;            // f16 weights
    unsigned short* w01h = wh;                          // 96x96
    unsigned short* w02h = wh + 9216;                   // 12x96
    unsigned short* w11h = wh + 10368;                  // 96x96
    unsigned short* w12h = wh + 19584;                  // 12x96
    unsigned short* w21h = wh + 20736;                  // 96x48
    unsigned short* w22h = wh + 25344;                  // 12x96

    cvtw_kernel<<<104, 256, 0, stream>>>(w0_1, w0_2, w1_1, w1_2, w2_1, w2_2, wh);
    perceive_kernel<128,128,7,7><<<NB*ND*128*128/256, 256, 0, stream>>>(x1, z1h);
    perceive_kernel< 64, 64,6,6><<<NB*ND*64*64/256,   256, 0, stream>>>(x2, z2h);

    res_mfma<0><<<NB*512, 256, 0, stream>>>(x0, nullptr, z1h, nullptr,
                                            w01h, b0_1, w02h, out);
    res_mfma<1><<<NB*128, 256, 0, stream>>>(nullptr, z1h, z2h, nullptr,
                                            w11h, b1_1, w12h,
                                            out + NB*ND*256*256);
    res_mfma<2><<<NB*32,  256, 0, stream>>>(nullptr, z2h, nullptr, x2,
                                            w21h, b2_1, w22h,
                                            out + NB*ND*256*256 + NB*ND*128*128);
}

// Round 7
// 141.667 us; speedup vs baseline: 2.8201x; 2.1953x over previous
//
#include <hip/hip_runtime.h>

// RecursiveNN — fully vectorized f16 pipeline.
// Feature order everywhere: k = f*16 + c (c<12 real, 12-15 zero-pad), so
// z is channel-last [b][y][x][64] and all A-builds are b128 copies / packed
// f16x8 math. W1 pre-permuted on device into MFMA fragment layout [kg][96][8].
// res kernels: 16x8 px tiles, 256 thr; A/H in LDS [kg][row][8]; W1/W2 frags
// read direct from global (L1-hot). res1/res2: barrier-free.
// R7 fix: cvtw thread guard 26496 -> 34176 (stale bound left w2h* unwritten
// -> garbage layer-2 weights -> absmax 3.0 in round 6).

namespace {
constexpr int NB = 16;
constexpr int ND = 12;
}

typedef __attribute__((ext_vector_type(8))) _Float16 f16x8;
typedef __attribute__((ext_vector_type(8))) short   s16x8;
typedef __attribute__((ext_vector_type(4))) float   f32x4;

__device__ __forceinline__ unsigned short f2h(float f) {
    return __builtin_bit_cast(unsigned short, (_Float16)f);   // RNE
}
__device__ __forceinline__ f16x8 splat8(float x) {
    _Float16 h = (_Float16)x;
    f16x8 v = {h,h,h,h,h,h,h,h};
    return v;
}
__device__ __forceinline__ f16x8 ld8(const unsigned short* p) {
    return __builtin_bit_cast(f16x8, *(const s16x8*)p);
}
__device__ __forceinline__ void st8(unsigned short* p, f16x8 v) {
    *(s16x8*)p = __builtin_bit_cast(s16x8, v);
}

__device__ __forceinline__ void up_taps(int y, int Hc, int& y0, int& y1, float& t1) {
    int j = y >> 1;
    if (y & 1) { y0 = j;            y1 = min(j+1, Hc-1); t1 = 0.25f; }
    else       { y0 = max(j-1, 0);  y1 = j;              t1 = 0.75f; }
}

// ---------------- perceive: x f32 planar -> z f16 channel-last [H][W][64] ---
template<int H, int W>
__global__ __launch_bounds__(256)
void perceive_kernel(const float* __restrict__ x, unsigned short* __restrict__ z) {
    constexpr int HW = H*W;
    constexpr int TPX = W/16, BPI = (H/8)*TPX;
    __shared__ unsigned short S[2880];   // [10][18][16] channel-last tile
    const int tid = threadIdx.x;
    const int gid = blockIdx.x;
    const int b   = gid / BPI;
    const int rem = gid - b*BPI;
    const int tx  = (rem % TPX)*16, ty = (rem / TPX)*8;

#pragma unroll
    for (int i = 0; i < 12; ++i) {
        int e = i*256 + tid;
        if (e < 2880) {
            int c = e / 180, r = e - c*180;
            int ri = r / 18, ci = r - ri*18;
            int gy = (ty - 1 + ri) & (H-1);
            int gx = (tx - 1 + ci) & (W-1);
            unsigned short v = 0;
            if (c < 12) v = f2h(x[(b*ND + c)*HW + gy*W + gx]);
            S[r*16 + c] = v;
        }
    }
    __syncthreads();

    const int p = tid >> 1, h = tid & 1;
    const int py = p >> 4, px = p & 15;
    const unsigned short* Sc = &S[(py*18 + px)*16 + 8*h];
    f16x8 n00=ld8(Sc+0),   n01=ld8(Sc+16),  n02=ld8(Sc+32);
    f16x8 n10=ld8(Sc+288), n11=ld8(Sc+304), n12=ld8(Sc+320);
    f16x8 n20=ld8(Sc+576), n21=ld8(Sc+592), n22=ld8(Sc+608);
    f16x8 two = splat8(2.f), twelve = splat8(12.f);
    f16x8 sx  = (n02-n00) + two*(n12-n10) + (n22-n20);
    f16x8 sy  = (n20-n00) + two*(n21-n01) + (n22-n02);
    f16x8 lap = ((n00+n02)+(n20+n22)) + two*((n01+n10)+(n12+n21)) - twelve*n11;
    unsigned short* zp = z + ((b*H + ty+py)*W + tx+px)*64 + 8*h;
    st8(zp+0,  n11);
    st8(zp+16, sx);
    st8(zp+32, sy);
    st8(zp+48, lap);
}

// ------- cvtw: pre-permute W1 into [kg][96][8] f16 fragments; W2 -> f16 -----
__global__ __launch_bounds__(256)
void cvtw_kernel(const float* __restrict__ w01, const float* __restrict__ w11,
                 const float* __restrict__ w21,
                 const float* __restrict__ w02, const float* __restrict__ w12,
                 const float* __restrict__ w22,
                 unsigned short* __restrict__ w1f0, unsigned short* __restrict__ w1f1,
                 unsigned short* __restrict__ w1f2,
                 unsigned short* __restrict__ w2h0, unsigned short* __restrict__ w2h1,
                 unsigned short* __restrict__ w2h2) {
    int i = blockIdx.x*256 + threadIdx.x;
    if (i >= 34176) return;                   // R7 fix (was 26496)
    if (i < 24576) {                          // w1f0 / w1f1: [16][96][8]
        const float* w = (i < 12288) ? w01 : w11;
        unsigned short* d = (i < 12288) ? w1f0 : w1f1;
        int e = (i < 12288) ? i : i - 12288;
        int kg = e / 768, rm = e - kg*768, n = rm >> 3, j = rm & 7;
        int kh = kg*8 + j;
        int orig;
        if (kh < 64) { int f = kh >> 4, c = kh & 15; orig = (c < 12) ? 4*c+f : -1; }
        else { int q = kh-64; int f = q >> 4, c = q & 15; orig = (c < 12) ? 48+4*c+f : -1; }
        d[e] = (orig >= 0) ? f2h(w[n*96 + orig]) : (unsigned short)0;
    } else if (i < 30720) {                   // w1f2: [8][96][8], K1=48
        int e = i - 24576;
        int kg = e / 768, rm = e - kg*768, n = rm >> 3, j = rm & 7;
        int kh = kg*8 + j;
        int f = kh >> 4, c = kh & 15;
        int orig = (c < 12) ? 4*c+f : -1;
        w1f2[e] = (orig >= 0) ? f2h(w21[n*48 + orig]) : (unsigned short)0;
    } else {                                  // w2h x3: [12][96]
        int e = i - 30720;
        const float* w = (e < 1152) ? w02 : (e < 2304) ? w12 : w22;
        unsigned short* d = (e < 1152) ? w2h0 : (e < 2304) ? w2h1 : w2h2;
        int q = (e >= 2304) ? e-2304 : (e >= 1152) ? e-1152 : e;
        d[q] = f2h(w[q]);
    }
}

// ---------------- fused per-resolution MFMA kernel --------------------------
template<int RES>
__global__ __launch_bounds__(256, 4)
void res_mfma(const float* __restrict__ x0f,
              const unsigned short* __restrict__ zown,
              const unsigned short* __restrict__ zc,
              const float* __restrict__ xres,
              const unsigned short* __restrict__ w1f,   // [NKG][96][8] f16
              const float* __restrict__ b1,
              const unsigned short* __restrict__ w2h,   // [12][96] f16
              float* __restrict__ out)
{
    constexpr int H  = (RES==0)?256:(RES==1)?128:64;
    constexpr int W  = H, Hc = H/2, Wc = W/2;
    constexpr int HW = H*W;
    constexpr int TPX = W/16, BPI = (H/8)*TPX;
    constexpr int NK  = (RES==2)?2:4;          // layer-1 k-steps (K=NK*32)
    constexpr int NKG = (RES==2)?12:16;        // Alds kgroups (H needs 12)

    __shared__ unsigned short Alds[NKG*128*8]; // [kg][row][8]; A then H
    __shared__ unsigned short S[(RES==0)?2880:8];

    const int tid = threadIdx.x;
    const int cpx = gridDim.x >> 3;            // grid % 8 == 0 for all RES
    const int gid = (blockIdx.x & 7)*cpx + (blockIdx.x >> 3);
    const int b   = gid / BPI;
    const int rem = gid - b*BPI;
    const int tx  = (rem % TPX)*16, ty = (rem / TPX)*8;

    const int wid = tid >> 6, lane = tid & 63;
    const int fr  = lane & 15, g = lane >> 4;
    const int p   = tid >> 1, h = tid & 1;
    const int py  = p >> 4, px = p & 15;
    const int gy  = ty + py, gx = tx + px;

    // ================= build A =================
    if (RES == 0) {
        const float* bp = x0f + b*ND*HW;
#pragma unroll
        for (int i = 0; i < 12; ++i) {
            int e = i*256 + tid;
            if (e < 2880) {
                int c = e / 180, r = e - c*180;
                int ri = r / 18, ci = r - ri*18;
                int sy2 = (ty - 1 + ri) & (H-1);
                int sx2 = (tx - 1 + ci) & (W-1);
                unsigned short v = 0;
                if (c < 12) v = f2h(bp[c*HW + sy2*W + sx2]);
                S[r*16 + c] = v;
            }
        }
        __syncthreads();
        const unsigned short* Sc = &S[(py*18 + px)*16 + 8*h];
        f16x8 n00=ld8(Sc+0),   n01=ld8(Sc+16),  n02=ld8(Sc+32);
        f16x8 n10=ld8(Sc+288), n11=ld8(Sc+304), n12=ld8(Sc+320);
        f16x8 n20=ld8(Sc+576), n21=ld8(Sc+592), n22=ld8(Sc+608);
        f16x8 two = splat8(2.f), twelve = splat8(12.f);
        f16x8 sx  = (n02-n00) + two*(n12-n10) + (n22-n20);
        f16x8 sy  = (n20-n00) + two*(n21-n01) + (n22-n02);
        f16x8 lap = ((n00+n02)+(n20+n22)) + two*((n01+n10)+(n12+n21)) - twelve*n11;
        st8(&Alds[(0+h)*1024 + p*8], n11);
        st8(&Alds[(2+h)*1024 + p*8], sx);
        st8(&Alds[(4+h)*1024 + p*8], sy);
        st8(&Alds[(6+h)*1024 + p*8], lap);
    } else {
        const unsigned short* src = &zown[((b*H + gy)*W + gx)*64 + 32*h];
#pragma unroll
        for (int j = 0; j < 4; ++j)
            *(s16x8*)&Alds[(4*h + j)*1024 + p*8] = *(const s16x8*)&src[8*j];
    }

    if (RES != 2) {
        // bilinear 2x upsample of coarse z (channel-last, global-direct taps)
        int ys0, ys1, xs0, xs1; float tyw, txw;
        up_taps(gy, Hc, ys0, ys1, tyw);
        up_taps(gx, Wc, xs0, xs1, txw);
        float wy0 = 1.f - tyw, wx0 = 1.f - txw;
        f16x8 w00 = splat8(wy0*wx0), w01v = splat8(wy0*txw);
        f16x8 w10 = splat8(tyw*wx0), w11v = splat8(tyw*txw);
        int o00 = ((b*Hc + ys0)*Wc + xs0)*64 + 32*h;
        int o01 = ((b*Hc + ys0)*Wc + xs1)*64 + 32*h;
        int o10 = ((b*Hc + ys1)*Wc + xs0)*64 + 32*h;
        int o11 = ((b*Hc + ys1)*Wc + xs1)*64 + 32*h;
#pragma unroll
        for (int j = 0; j < 4; ++j) {
            f16x8 t00 = ld8(&zc[o00 + 8*j]);
            f16x8 t01 = ld8(&zc[o01 + 8*j]);
            f16x8 t10 = ld8(&zc[o10 + 8*j]);
            f16x8 t11 = ld8(&zc[o11 + 8*j]);
            f16x8 v = t00*w00 + t01*w01v + t10*w10 + t11*w11v;
            st8(&Alds[(8 + 4*h + j)*1024 + p*8], v);
        }
    }

    // ================= layer 1 MFMA (B-frags direct from global) ===========
    f32x4 acc[2][6] = {};
#pragma unroll
    for (int ks = 0; ks < NK; ++ks) {
        const int kga = ks*4 + g;
        f16x8 a0 = ld8(&Alds[kga*1024 + (wid*32 +      fr)*8]);
        f16x8 a1 = ld8(&Alds[kga*1024 + (wid*32 + 16 + fr)*8]);
#pragma unroll
        for (int nt = 0; nt < 6; ++nt) {
            f16x8 bb = ld8(&w1f[(kga*96 + nt*16 + fr)*8]);
            acc[0][nt] = __builtin_amdgcn_mfma_f32_16x16x32_f16(a0, bb, acc[0][nt], 0, 0, 0);
            acc[1][nt] = __builtin_amdgcn_mfma_f32_16x16x32_f16(a1, bb, acc[1][nt], 0, 0, 0);
        }
    }

    // ================= bias + relu -> H (own-wave rows) =================
    float bv[6];
#pragma unroll
    for (int nt = 0; nt < 6; ++nt) bv[nt] = b1[nt*16 + fr];
#pragma unroll
    for (int nt = 0; nt < 6; ++nt)
#pragma unroll
        for (int m = 0; m < 2; ++m)
#pragma unroll
            for (int rg = 0; rg < 4; ++rg) {
                float hh = fmaxf(acc[m][nt][rg] + bv[nt], 0.f);
                int k = nt*16 + fr;
                int row = wid*32 + m*16 + g*4 + rg;
                Alds[(k >> 3)*1024 + row*8 + (k & 7)] = f2h(hh);
            }

    // ================= layer 2 MFMA (K=96, N=16 padded) =================
    f16x8 b2f[3];
#pragma unroll
    for (int ks = 0; ks < 3; ++ks) {
        s16x8 v = {0,0,0,0,0,0,0,0};
        if (fr < 12) v = *(const s16x8*)&w2h[fr*96 + ks*32 + g*8];
        b2f[ks] = __builtin_bit_cast(f16x8, v);
    }
    f32x4 acc2[2] = {};
#pragma unroll
    for (int ks = 0; ks < 3; ++ks) {
        const int kga = ks*4 + g;
#pragma unroll
        for (int m = 0; m < 2; ++m) {
            f16x8 ah = ld8(&Alds[kga*1024 + (wid*32 + m*16 + fr)*8]);
            acc2[m] = __builtin_amdgcn_mfma_f32_16x16x32_f16(ah, b2f[ks], acc2[m], 0, 0, 0);
        }
    }

    // ================= store =================
    if (fr < 12) {
        const int chbase = (b*ND + fr)*HW;
#pragma unroll
        for (int m = 0; m < 2; ++m) {
            int oy = ty + wid*2 + m;
            int ox = tx + g*4;
            float4 vv;
            vv.x = acc2[m][0]; vv.y = acc2[m][1];
            vv.z = acc2[m][2]; vv.w = acc2[m][3];
            if (RES == 2) {
                const float4 rr = *(const float4*)&xres[chbase + oy*W + ox];
                vv.x += rr.x; vv.y += rr.y; vv.z += rr.z; vv.w += rr.w;
            }
            *(float4*)&out[chbase + oy*W + ox] = vv;
        }
    }
}

extern "C" void kernel_launch(void* const* d_in, const int* in_sizes, int n_in,
                              void* d_out, int out_size, void* d_ws, size_t ws_size,
                              hipStream_t stream) {
    const float* x0   = (const float*)d_in[0];
    const float* x1   = (const float*)d_in[1];
    const float* x2   = (const float*)d_in[2];
    const float* w0_1 = (const float*)d_in[3];
    const float* b0_1 = (const float*)d_in[4];
    const float* w0_2 = (const float*)d_in[5];
    const float* w1_1 = (const float*)d_in[6];
    const float* b1_1 = (const float*)d_in[7];
    const float* w1_2 = (const float*)d_in[8];
    const float* w2_1 = (const float*)d_in[9];
    const float* b2_1 = (const float*)d_in[10];
    const float* w2_2 = (const float*)d_in[11];
    float* out = (float*)d_out;

    unsigned short* z1h  = (unsigned short*)d_ws;       // [16][128][128][64]
    unsigned short* z2h  = z1h + 16*128*128*64;         // [16][64][64][64]
    unsigned short* w1f0 = z2h + 16*64*64*64;           // [16][96][8]
    unsigned short* w1f1 = w1f0 + 12288;
    unsigned short* w1f2 = w1f1 + 12288;                // [8][96][8]
    unsigned short* w2h0 = w1f2 + 6144;                 // [12][96]
    unsigned short* w2h1 = w2h0 + 1152;
    unsigned short* w2h2 = w2h1 + 1152;

    cvtw_kernel<<<134, 256, 0, stream>>>(w0_1, w1_1, w2_1, w0_2, w1_2, w2_2,
                                         w1f0, w1f1, w1f2, w2h0, w2h1, w2h2);
    perceive_kernel<128,128><<<NB*128, 256, 0, stream>>>(x1, z1h);
    perceive_kernel< 64, 64><<<NB*32,  256, 0, stream>>>(x2, z2h);

    res_mfma<0><<<NB*512, 256, 0, stream>>>(x0, nullptr, z1h, nullptr,
                                            w1f0, b0_1, w2h0, out);
    res_mfma<1><<<NB*128, 256, 0, stream>>>(nullptr, z1h, z2h, nullptr,
                                            w1f1, b1_1, w2h1,
                                            out + NB*ND*256*256);
    res_mfma<2><<<NB*32,  256, 0, stream>>>(nullptr, z2h, nullptr, x2,
                                            w1f2, b2_1, w2h2,
                                            out + NB*ND*256*256 + NB*ND*128*128);
}